// Round 1
// baseline (679.965 us; speedup 1.0000x reference)
//
#include <hip/hip_runtime.h>
#include <hip/hip_bf16.h>
#include <cstdint>

// ---------------------------------------------------------------------------
// LSTM cell fused forward on MI355X (gfx950).
//   gates = [input|hidden] @ [W;U] + b   (fp32 via 3-product bf16 MFMA emulation)
//   elementwise LSTM epilogue fused into gate GEMM
//   logits = h_new @ W_h + b_h           (same bf16x3 GEMM)
//   log_softmax row-wise
// ---------------------------------------------------------------------------

#define B_DIM   8192
#define K1      2048   // IN + H
#define N1      4096   // 4*H
#define H_DIM   1024
#define OUT_DIM 1024

typedef __attribute__((ext_vector_type(8))) __bf16 bf16x8;
typedef __attribute__((ext_vector_type(4))) float  f32x4;

// round-to-nearest-even float -> bf16 bits (finite inputs only)
__device__ __forceinline__ unsigned short f2bf(float f) {
    unsigned int u = __float_as_uint(f);
    u += 0x7FFFu + ((u >> 16) & 1u);
    return (unsigned short)(u >> 16);
}
__device__ __forceinline__ float bf2f(unsigned short s) {
    return __uint_as_float(((unsigned int)s) << 16);
}

__device__ __forceinline__ void gload_lds16(const void* g, void* l) {
    __builtin_amdgcn_global_load_lds(
        (const __attribute__((address_space(1))) void*)g,
        (__attribute__((address_space(3))) void*)l, 16, 0, 0);
}

// ---------------------------------------------------------------------------
// Split X = [input | hidden] (row-major [8192][2048]) into bf16 hi/lo.
// ---------------------------------------------------------------------------
__global__ __launch_bounds__(256) void k_split_x(
    const float* __restrict__ input, const float* __restrict__ hidden,
    unsigned short* __restrict__ xhi, unsigned short* __restrict__ xlo) {
    const int64_t n4 = (int64_t)B_DIM * K1 / 4;
    for (int64_t i = (int64_t)blockIdx.x * blockDim.x + threadIdx.x; i < n4;
         i += (int64_t)gridDim.x * blockDim.x) {
        int64_t e = i * 4;
        int row = (int)(e >> 11);
        int col = (int)(e & 2047);
        const float* src = (col < 1024) ? (input + (int64_t)row * 1024 + col)
                                        : (hidden + (int64_t)row * 1024 + (col - 1024));
        float4 v = *(const float4*)src;
        ushort4 hv, lv;
        hv.x = f2bf(v.x); lv.x = f2bf(v.x - bf2f(hv.x));
        hv.y = f2bf(v.y); lv.y = f2bf(v.y - bf2f(hv.y));
        hv.z = f2bf(v.z); lv.z = f2bf(v.z - bf2f(hv.z));
        hv.w = f2bf(v.w); lv.w = f2bf(v.w - bf2f(hv.w));
        *(ushort4*)(xhi + e) = hv;
        *(ushort4*)(xlo + e) = lv;
    }
}

// ---------------------------------------------------------------------------
// Transpose + split a [1024 x 1024] fp32 weight into bf16 hi/lo at
// dst[n'][k], n' = h*nmul + ng, k = koff + klocal.  (LDS tiled transpose)
// ---------------------------------------------------------------------------
__global__ __launch_bounds__(256) void k_trans_split(
    const float* __restrict__ src,
    unsigned short* __restrict__ dhi, unsigned short* __restrict__ dlo,
    int nmul, int ng, int dstK, int koff) {
    __shared__ float t[64][65];
    const int h0 = blockIdx.x * 64;
    const int k0 = blockIdx.y * 64;
    const int tx = threadIdx.x & 63, ty = threadIdx.x >> 6;
    #pragma unroll
    for (int r = ty; r < 64; r += 4)
        t[r][tx] = src[(int64_t)(k0 + r) * 1024 + h0 + tx];
    __syncthreads();
    #pragma unroll
    for (int r = ty; r < 64; r += 4) {
        float v = t[tx][r];
        unsigned short hi = f2bf(v);
        unsigned short lo = f2bf(v - bf2f(hi));
        int64_t o = (int64_t)((h0 + r) * nmul + ng) * dstK + koff + k0 + tx;
        dhi[o] = hi;
        dlo[o] = lo;
    }
}

// bias4[n'] = b_g[h], n' = 4h+g
__global__ __launch_bounds__(256) void k_pack_bias(
    const float* __restrict__ bf_, const float* __restrict__ bi_,
    const float* __restrict__ bc_, const float* __restrict__ bo_,
    float* __restrict__ bias4) {
    int n = blockIdx.x * 256 + threadIdx.x;
    if (n < 4096) {
        int g = n & 3, h = n >> 2;
        const float* p = (g == 0) ? bf_ : (g == 1) ? bi_ : (g == 2) ? bc_ : bo_;
        bias4[n] = p[h];
    }
}

// ---------------------------------------------------------------------------
// bf16x3 GEMM, 128x128 tile, BK=32, 4 waves (2x2 of 64x64), 16x16x32 MFMA.
// A: [M][K] bf16 hi/lo row-major.  B: [N][K] bf16 hi/lo row-major (B^T form).
// LDS row layout per tile row: [hi 4x16B | lo 4x16B] = 128B, XOR slot swizzle
// (slot ^= row&7) applied identically on the staging SOURCE and the ds_read.
// EPI==1: gate epilogue (bias+activations+LSTM update, gate-interleaved cols)
// EPI==0: bias add + fp32 store (logits)
// ---------------------------------------------------------------------------
template <int EPI>
__global__ __launch_bounds__(256, 2) void k_gemm(
    const unsigned short* __restrict__ Ahi, const unsigned short* __restrict__ Alo,
    const unsigned short* __restrict__ Bhi, const unsigned short* __restrict__ Blo,
    int K, int Ncols,
    const float* __restrict__ bias,
    const float* __restrict__ cell,
    float* __restrict__ out0,
    unsigned short* __restrict__ hhi, unsigned short* __restrict__ hlo) {
    __shared__ char smem[32768];  // A tile 16KB | B tile 16KB

    const int tid  = threadIdx.x;
    const int lane = tid & 63;
    const int w    = tid >> 6;           // wave 0..3
    const int wr   = (w >> 1) * 64;      // wave row offset in 128-tile
    const int wc   = (w & 1) * 64;       // wave col offset
    const int m0   = blockIdx.y * 128;
    const int n0   = blockIdx.x * 128;

    f32x4 acc[4][4];
    #pragma unroll
    for (int i = 0; i < 4; i++)
        #pragma unroll
        for (int j = 0; j < 4; j++) acc[i][j] = (f32x4){0.f, 0.f, 0.f, 0.f};

    // --- staging source precompute (global side carries the swizzle) ---
    const int sr = tid >> 3;                       // row within 32-row chunk
    const int s2 = (tid & 7) ^ (sr & 7);           // logical slot 0..7
    const unsigned short* Asrc =
        ((s2 < 4) ? Ahi : Alo) + (int64_t)(m0 + sr) * K + (s2 & 3) * 8;
    const unsigned short* Bsrc =
        ((s2 < 4) ? Bhi : Blo) + (int64_t)(n0 + sr) * K + (s2 & 3) * 8;

    // --- ds_read side swizzle ---
    const int q  = lane >> 4;      // k-group 0..3
    const int fr = lane & 15;      // fragment row/col
    const int sw = lane & 7;
    const int hiSlot = ((q)     ^ sw) << 4;
    const int loSlot = ((q + 4) ^ sw) << 4;

    for (int kt = 0; kt < K; kt += 32) {
        __syncthreads();  // previous-iteration LDS reads done
        #pragma unroll
        for (int i = 0; i < 4; i++) {
            gload_lds16(Asrc + (int64_t)i * 32 * K + kt, smem + i * 4096 + w * 1024);
            gload_lds16(Bsrc + (int64_t)i * 32 * K + kt, smem + 16384 + i * 4096 + w * 1024);
        }
        __syncthreads();  // loads landed (compiler drains vmcnt before barrier)

        bf16x8 ah[4], al[4], bh[4], bl[4];
        #pragma unroll
        for (int mi = 0; mi < 4; mi++) {
            const char* rp = smem + (wr + mi * 16 + fr) * 128;
            ah[mi] = *(const bf16x8*)(rp + hiSlot);
            al[mi] = *(const bf16x8*)(rp + loSlot);
        }
        #pragma unroll
        for (int ni = 0; ni < 4; ni++) {
            const char* rp = smem + 16384 + (wc + ni * 16 + fr) * 128;
            bh[ni] = *(const bf16x8*)(rp + hiSlot);
            bl[ni] = *(const bf16x8*)(rp + loSlot);
        }
        #pragma unroll
        for (int mi = 0; mi < 4; mi++)
            #pragma unroll
            for (int ni = 0; ni < 4; ni++) {
                acc[mi][ni] = __builtin_amdgcn_mfma_f32_16x16x32_bf16(ah[mi], bh[ni], acc[mi][ni], 0, 0, 0);
                acc[mi][ni] = __builtin_amdgcn_mfma_f32_16x16x32_bf16(ah[mi], bl[ni], acc[mi][ni], 0, 0, 0);
                acc[mi][ni] = __builtin_amdgcn_mfma_f32_16x16x32_bf16(al[mi], bh[ni], acc[mi][ni], 0, 0, 0);
            }
    }

    // --- epilogue ---
    if constexpr (EPI == 0) {
        #pragma unroll
        for (int mi = 0; mi < 4; mi++)
            #pragma unroll
            for (int ni = 0; ni < 4; ni++) {
                int col = n0 + wc + ni * 16 + fr;
                int rowb = m0 + wr + mi * 16 + q * 4;
                float bb = bias[col];
                #pragma unroll
                for (int j = 0; j < 4; j++)
                    out0[(int64_t)(rowb + j) * Ncols + col] = acc[mi][ni][j] + bb;
            }
    } else {
        const int lb = lane & ~3;  // quad base: lanes lb..lb+3 hold gates f,i,c,o of same h
        const int64_t OFF_H = (int64_t)B_DIM * H_DIM;      // hidden_state slot
        const int64_t OFF_C = (int64_t)2 * B_DIM * H_DIM;  // cell_state slot
        #pragma unroll
        for (int mi = 0; mi < 4; mi++)
            #pragma unroll
            for (int ni = 0; ni < 4; ni++) {
                int col = n0 + wc + ni * 16 + fr;  // n' = 4h+g
                int g = col & 3;
                int h = col >> 2;
                float bb = bias[col];
                int rowb = m0 + wr + mi * 16 + q * 4;
                #pragma unroll
                for (int j = 0; j < 4; j++) {
                    float v = acc[mi][ni][j] + bb;
                    float a = (g == 2) ? tanhf(v) : 1.0f / (1.0f + expf(-v));
                    float fg = __shfl(a, lb + 0, 64);
                    float ig = __shfl(a, lb + 1, 64);
                    float ct = __shfl(a, lb + 2, 64);
                    float og = __shfl(a, lb + 3, 64);
                    int row = rowb + j;
                    int64_t o = (int64_t)row * H_DIM + h;
                    float cn = fg * cell[o] + ig * ct;
                    float hn = og * tanhf(cn);
                    int role = lane & 3;
                    if (role == 0) {
                        out0[OFF_C + o] = cn;
                    } else if (role == 1) {
                        out0[OFF_H + o] = hn;
                    } else if (role == 2) {
                        hhi[o] = f2bf(hn);
                    } else {
                        unsigned short t = f2bf(hn);
                        hlo[o] = f2bf(hn - bf2f(t));
                    }
                }
            }
    }
}

// ---------------------------------------------------------------------------
// Row-wise log_softmax over [8192][1024]: one block per row.
// ---------------------------------------------------------------------------
__global__ __launch_bounds__(256) void k_logsoftmax(
    const float* __restrict__ logits, float* __restrict__ out) {
    const int row = blockIdx.x;
    const int t = threadIdx.x;
    const float* x = logits + (int64_t)row * 1024;
    float4 v = *(const float4*)(x + t * 4);

    float m = fmaxf(fmaxf(v.x, v.y), fmaxf(v.z, v.w));
    #pragma unroll
    for (int off = 1; off < 64; off <<= 1) m = fmaxf(m, __shfl_xor(m, off, 64));
    __shared__ float sm[4];
    __shared__ float ssum[4];
    int ln = t & 63, wv = t >> 6;
    if (ln == 0) sm[wv] = m;
    __syncthreads();
    m = fmaxf(fmaxf(sm[0], sm[1]), fmaxf(sm[2], sm[3]));

    float s = expf(v.x - m) + expf(v.y - m) + expf(v.z - m) + expf(v.w - m);
    #pragma unroll
    for (int off = 1; off < 64; off <<= 1) s += __shfl_xor(s, off, 64);
    if (ln == 0) ssum[wv] = s;
    __syncthreads();
    s = ssum[0] + ssum[1] + ssum[2] + ssum[3];

    float lse = m + logf(s);
    float4 o;
    o.x = v.x - lse; o.y = v.y - lse; o.z = v.z - lse; o.w = v.w - lse;
    *(float4*)(out + (int64_t)row * 1024 + t * 4) = o;
}

// ---------------------------------------------------------------------------
extern "C" void kernel_launch(void* const* d_in, const int* in_sizes, int n_in,
                              void* d_out, int out_size, void* d_ws, size_t ws_size,
                              hipStream_t stream) {
    const float* input  = (const float*)d_in[0];
    const float* hidden = (const float*)d_in[1];
    const float* cell   = (const float*)d_in[2];
    const float* W_f = (const float*)d_in[3];
    const float* U_f = (const float*)d_in[4];
    const float* b_f = (const float*)d_in[5];
    const float* W_i = (const float*)d_in[6];
    const float* U_i = (const float*)d_in[7];
    const float* b_i = (const float*)d_in[8];
    const float* W_c = (const float*)d_in[9];
    const float* U_c = (const float*)d_in[10];
    const float* b_c = (const float*)d_in[11];
    const float* W_o = (const float*)d_in[12];
    const float* U_o = (const float*)d_in[13];
    const float* b_o = (const float*)d_in[14];
    const float* W_h = (const float*)d_in[15];
    const float* b_h = (const float*)d_in[16];
    float* out = (float*)d_out;

    char* ws = (char*)d_ws;
    // workspace layout (bytes)
    unsigned short* xhi  = (unsigned short*)(ws);               // 32 MB
    unsigned short* xlo  = (unsigned short*)(ws + 33554432);    // 32 MB
    unsigned short* wuhi = (unsigned short*)(ws + 67108864);    // 16 MB
    unsigned short* wulo = (unsigned short*)(ws + 83886080);    // 16 MB
    unsigned short* hhi  = (unsigned short*)(ws + 100663296);   // 16 MB
    unsigned short* hlo  = (unsigned short*)(ws + 117440512);   // 16 MB
    unsigned short* whhi = (unsigned short*)(ws + 134217728);   // 2 MB
    unsigned short* whlo = (unsigned short*)(ws + 136314880);   // 2 MB
    float*          bias4 = (float*)(ws + 138412032);           // 16 KB
    float*          logits = (float*)(ws);                      // aliases X (free after gate GEMM)
    if (ws_size < (size_t)138428416) return;  // insufficient scratch

    k_split_x<<<2048, 256, 0, stream>>>(input, hidden, xhi, xlo);

    const float* Warr[8] = {W_f, W_i, W_c, W_o, U_f, U_i, U_c, U_o};
    for (int a = 0; a < 8; a++)
        k_trans_split<<<dim3(16, 16), 256, 0, stream>>>(
            Warr[a], wuhi, wulo, 4, a & 3, 2048, (a >> 2) * 1024);
    k_trans_split<<<dim3(16, 16), 256, 0, stream>>>(W_h, whhi, whlo, 1, 0, 1024, 0);
    k_pack_bias<<<16, 256, 0, stream>>>(b_f, b_i, b_c, b_o, bias4);

    // gates GEMM + fused LSTM epilogue: M=8192, N'=4096, K=2048
    k_gemm<1><<<dim3(32, 64), 256, 0, stream>>>(
        xhi, xlo, wuhi, wulo, 2048, 4096, bias4, cell, out, hhi, hlo);

    // logits GEMM: M=8192, N=1024, K=1024
    k_gemm<0><<<dim3(8, 64), 256, 0, stream>>>(
        hhi, hlo, whhi, whlo, 1024, 1024, b_h, nullptr, logits, nullptr, nullptr);

    k_logsoftmax<<<8192, 256, 0, stream>>>(logits, out);
}

// Round 2
// 646.537 us; speedup vs baseline: 1.0517x; 1.0517x over previous
//
#include <hip/hip_runtime.h>
#include <hip/hip_bf16.h>
#include <cstdint>

// ---------------------------------------------------------------------------
// LSTM cell fused forward on MI355X (gfx950).
//   gates = [input|hidden] @ [W;U] + b   (fp32 via 3-product bf16 MFMA emulation)
//   gate GEMM: 256x256 tile, 8-phase schedule, counted vmcnt (T2+T3+T4+T5)
//   elementwise LSTM epilogue fused into gate GEMM
//   logits = h_new @ W_h + b_h           (128^2 bf16x3 GEMM)
//   log_softmax row-wise
// ---------------------------------------------------------------------------

#define B_DIM   8192
#define K1      2048   // IN + H
#define N1      4096   // 4*H
#define H_DIM   1024
#define OUT_DIM 1024

typedef __attribute__((ext_vector_type(8))) __bf16 bf16x8;
typedef __attribute__((ext_vector_type(4))) float  f32x4;

__device__ __forceinline__ unsigned short f2bf(float f) {
    unsigned int u = __float_as_uint(f);
    u += 0x7FFFu + ((u >> 16) & 1u);
    return (unsigned short)(u >> 16);
}
__device__ __forceinline__ float bf2f(unsigned short s) {
    return __uint_as_float(((unsigned int)s) << 16);
}

__device__ __forceinline__ void gload_lds16(const void* g, void* l) {
    __builtin_amdgcn_global_load_lds(
        (const __attribute__((address_space(1))) void*)g,
        (__attribute__((address_space(3))) void*)l, 16, 0, 0);
}

__device__ __forceinline__ f32x4 mfma16(bf16x8 a, bf16x8 b, f32x4 c) {
    return __builtin_amdgcn_mfma_f32_16x16x32_bf16(a, b, c, 0, 0, 0);
}

__device__ __forceinline__ void phase_barrier() {
    __builtin_amdgcn_sched_barrier(0);
    __builtin_amdgcn_s_barrier();
    __builtin_amdgcn_sched_barrier(0);
}

// ---------------------------------------------------------------------------
// Split X = [input | hidden] (row-major [8192][2048]) into bf16 hi/lo.
// ---------------------------------------------------------------------------
__global__ __launch_bounds__(256) void k_split_x(
    const float* __restrict__ input, const float* __restrict__ hidden,
    unsigned short* __restrict__ xhi, unsigned short* __restrict__ xlo) {
    const int64_t n4 = (int64_t)B_DIM * K1 / 4;
    for (int64_t i = (int64_t)blockIdx.x * blockDim.x + threadIdx.x; i < n4;
         i += (int64_t)gridDim.x * blockDim.x) {
        int64_t e = i * 4;
        int row = (int)(e >> 11);
        int col = (int)(e & 2047);
        const float* src = (col < 1024) ? (input + (int64_t)row * 1024 + col)
                                        : (hidden + (int64_t)row * 1024 + (col - 1024));
        float4 v = *(const float4*)src;
        ushort4 hv, lv;
        hv.x = f2bf(v.x); lv.x = f2bf(v.x - bf2f(hv.x));
        hv.y = f2bf(v.y); lv.y = f2bf(v.y - bf2f(hv.y));
        hv.z = f2bf(v.z); lv.z = f2bf(v.z - bf2f(hv.z));
        hv.w = f2bf(v.w); lv.w = f2bf(v.w - bf2f(hv.w));
        *(ushort4*)(xhi + e) = hv;
        *(ushort4*)(xlo + e) = lv;
    }
}

// ---------------------------------------------------------------------------
// Transpose + split a [1024 x 1024] fp32 weight into bf16 hi/lo at
// dst[n'][k], n' = h*nmul + ng, k = koff + klocal.
// ---------------------------------------------------------------------------
__global__ __launch_bounds__(256) void k_trans_split(
    const float* __restrict__ src,
    unsigned short* __restrict__ dhi, unsigned short* __restrict__ dlo,
    int nmul, int ng, int dstK, int koff) {
    __shared__ float t[64][65];
    const int h0 = blockIdx.x * 64;
    const int k0 = blockIdx.y * 64;
    const int tx = threadIdx.x & 63, ty = threadIdx.x >> 6;
    #pragma unroll
    for (int r = ty; r < 64; r += 4)
        t[r][tx] = src[(int64_t)(k0 + r) * 1024 + h0 + tx];
    __syncthreads();
    #pragma unroll
    for (int r = ty; r < 64; r += 4) {
        float v = t[tx][r];
        unsigned short hi = f2bf(v);
        unsigned short lo = f2bf(v - bf2f(hi));
        int64_t o = (int64_t)((h0 + r) * nmul + ng) * dstK + koff + k0 + tx;
        dhi[o] = hi;
        dlo[o] = lo;
    }
}

// bias4[n'] = b_g[h], n' = 4h+g
__global__ __launch_bounds__(256) void k_pack_bias(
    const float* __restrict__ bf_, const float* __restrict__ bi_,
    const float* __restrict__ bc_, const float* __restrict__ bo_,
    float* __restrict__ bias4) {
    int n = blockIdx.x * 256 + threadIdx.x;
    if (n < 4096) {
        int g = n & 3, h = n >> 2;
        const float* p = (g == 0) ? bf_ : (g == 1) ? bi_ : (g == 2) ? bc_ : bo_;
        bias4[n] = p[h];
    }
}

// ---------------------------------------------------------------------------
// GATE GEMM: bf16x3, 256x256 tile, BK=32, 8 waves (2M x 4N), 8-phase-style
// schedule with counted vmcnt(6), double-buffered 128KB LDS.
// A: [8192][2048] bf16 hi/lo.  B: [4096][2048] bf16 hi/lo (B^T, n'=4h+g).
// LDS row = 128B: [hi 4x16B | lo 4x16B], slot XOR (row&7) swizzle carried on
// the global staging source; linear global_load_lds dest (rule 21).
// Fused LSTM epilogue.
// ---------------------------------------------------------------------------
#define NT (K1 / 32)  // 64 K-tiles

__global__ __launch_bounds__(512, 2) void k_gate_gemm256(
    const unsigned short* __restrict__ Ahi, const unsigned short* __restrict__ Alo,
    const unsigned short* __restrict__ Bhi, const unsigned short* __restrict__ Blo,
    const float* __restrict__ bias,
    const float* __restrict__ cell,
    float* __restrict__ out0,
    unsigned short* __restrict__ hhi, unsigned short* __restrict__ hlo) {
    extern __shared__ char smem[];  // 131072: buf{0,1} x [A 32KB | B 32KB]

    const int tid  = threadIdx.x;
    const int lane = tid & 63;
    const int w    = tid >> 6;             // wave 0..7
    const int wr   = (w >> 2) * 128;       // wave row offset (2 M-waves)
    const int wc   = (w & 3) * 64;         // wave col offset (4 N-waves)

    // XCD-aware swizzle: 512 blocks, 512%8==0 -> simple form valid
    const int bid = blockIdx.x;
    const int swz = (bid & 7) * 64 + (bid >> 3);
    const int m0  = (swz >> 4) * 256;      // 32 m-panels
    const int n0  = (swz & 15) * 256;      // 16 n-panels

    f32x4 acc[8][4];
    #pragma unroll
    for (int i = 0; i < 8; i++)
        #pragma unroll
        for (int j = 0; j < 4; j++) acc[i][j] = (f32x4){0.f, 0.f, 0.f, 0.f};

    // --- staging source (global side carries the swizzle) ---
    const int sr = tid >> 3;               // 0..63 (row within 64-row chunk)
    const int s2 = (tid & 7) ^ (sr & 7);   // logical slot
    const unsigned short* As =
        ((s2 < 4) ? Ahi : Alo) + (int64_t)(m0 + sr) * K1 + (s2 & 3) * 8;
    const unsigned short* Bs =
        ((s2 < 4) ? Bhi : Blo) + (int64_t)(n0 + sr) * K1 + (s2 & 3) * 8;
    const int ldsOff = tid * 16;           // linear dest within a 8KB chunk

    auto stageA = [&](int buf, int chunk, int kt) {
        gload_lds16(As + (int64_t)chunk * 64 * K1 + kt,
                    smem + buf * 65536 + chunk * 8192 + ldsOff);
    };
    auto stageB = [&](int buf, int chunk, int kt) {
        gload_lds16(Bs + (int64_t)chunk * 64 * K1 + kt,
                    smem + buf * 65536 + 32768 + chunk * 8192 + ldsOff);
    };

    // --- ds_read side swizzle ---
    const int q  = lane >> 4;
    const int fr = lane & 15;
    const int sw = lane & 7;
    const int hiSlot = (q ^ sw) << 4;
    const int loSlot = ((q + 4) ^ sw) << 4;

    // ---- prologue: tile0 fully, tile1 minus A1/A3 ----
    stageB(0, 0, 0); stageB(0, 1, 0); stageB(0, 2, 0); stageB(0, 3, 0);
    stageA(0, 0, 0); stageA(0, 2, 0); stageA(0, 1, 0); stageA(0, 3, 0);
    stageB(1, 0, 32); stageB(1, 1, 32); stageB(1, 2, 32); stageB(1, 3, 32);
    stageA(1, 0, 32); stageA(1, 2, 32);
    asm volatile("s_waitcnt vmcnt(6)" ::: "memory");
    phase_barrier();

    #pragma unroll 2
    for (int t = 0; t < NT; ++t) {
        const int c = t & 1;
        const char* sA = smem + (c << 16);
        const char* sB = sA + 32768;
        const int ktD = (t + 1) * 32;      // deferred pieces of tile t+1
        const int ktC = (t + 2) * 32;      // prefetch tile t+2

        bf16x8 bh[4], bl[4];

        // ---- phase 0: deferred A1/A3 of t+1; read B(all)+A(mi0,1); MFMA ----
        if (t < NT - 1) { stageA(c ^ 1, 1, ktD); stageA(c ^ 1, 3, ktD); }
        #pragma unroll
        for (int ni = 0; ni < 4; ni++) {
            const char* rp = sB + (wc + ni * 16 + fr) * 128;
            bh[ni] = *(const bf16x8*)(rp + hiSlot);
            bl[ni] = *(const bf16x8*)(rp + loSlot);
        }
        {
            const char* rp0 = sA + (wr + 0 * 16 + fr) * 128;
            const char* rp1 = sA + (wr + 1 * 16 + fr) * 128;
            bf16x8 ah0 = *(const bf16x8*)(rp0 + hiSlot), al0 = *(const bf16x8*)(rp0 + loSlot);
            bf16x8 ah1 = *(const bf16x8*)(rp1 + hiSlot), al1 = *(const bf16x8*)(rp1 + loSlot);
            __builtin_amdgcn_s_setprio(1);
            #pragma unroll
            for (int ni = 0; ni < 4; ni++) {
                acc[0][ni] = mfma16(ah0, bh[ni], acc[0][ni]);
                acc[0][ni] = mfma16(ah0, bl[ni], acc[0][ni]);
                acc[0][ni] = mfma16(al0, bh[ni], acc[0][ni]);
                acc[1][ni] = mfma16(ah1, bh[ni], acc[1][ni]);
                acc[1][ni] = mfma16(ah1, bl[ni], acc[1][ni]);
                acc[1][ni] = mfma16(al1, bh[ni], acc[1][ni]);
            }
            __builtin_amdgcn_s_setprio(0);
        }
        phase_barrier();

        // ---- phase 1: stage t+2 B; MFMA mi2,3 ----
        if (t < NT - 2) { stageB(c, 0, ktC); stageB(c, 1, ktC); stageB(c, 2, ktC); stageB(c, 3, ktC); }
        {
            const char* rp0 = sA + (wr + 2 * 16 + fr) * 128;
            const char* rp1 = sA + (wr + 3 * 16 + fr) * 128;
            bf16x8 ah0 = *(const bf16x8*)(rp0 + hiSlot), al0 = *(const bf16x8*)(rp0 + loSlot);
            bf16x8 ah1 = *(const bf16x8*)(rp1 + hiSlot), al1 = *(const bf16x8*)(rp1 + loSlot);
            __builtin_amdgcn_s_setprio(1);
            #pragma unroll
            for (int ni = 0; ni < 4; ni++) {
                acc[2][ni] = mfma16(ah0, bh[ni], acc[2][ni]);
                acc[2][ni] = mfma16(ah0, bl[ni], acc[2][ni]);
                acc[2][ni] = mfma16(al0, bh[ni], acc[2][ni]);
                acc[3][ni] = mfma16(ah1, bh[ni], acc[3][ni]);
                acc[3][ni] = mfma16(ah1, bl[ni], acc[3][ni]);
                acc[3][ni] = mfma16(al1, bh[ni], acc[3][ni]);
            }
            __builtin_amdgcn_s_setprio(0);
        }
        phase_barrier();

        // ---- phase 2: stage t+2 A0/A2; MFMA mi4,5 ----
        if (t < NT - 2) { stageA(c, 0, ktC); stageA(c, 2, ktC); }
        {
            const char* rp0 = sA + (wr + 4 * 16 + fr) * 128;
            const char* rp1 = sA + (wr + 5 * 16 + fr) * 128;
            bf16x8 ah0 = *(const bf16x8*)(rp0 + hiSlot), al0 = *(const bf16x8*)(rp0 + loSlot);
            bf16x8 ah1 = *(const bf16x8*)(rp1 + hiSlot), al1 = *(const bf16x8*)(rp1 + loSlot);
            __builtin_amdgcn_s_setprio(1);
            #pragma unroll
            for (int ni = 0; ni < 4; ni++) {
                acc[4][ni] = mfma16(ah0, bh[ni], acc[4][ni]);
                acc[4][ni] = mfma16(ah0, bl[ni], acc[4][ni]);
                acc[4][ni] = mfma16(al0, bh[ni], acc[4][ni]);
                acc[5][ni] = mfma16(ah1, bh[ni], acc[5][ni]);
                acc[5][ni] = mfma16(ah1, bl[ni], acc[5][ni]);
                acc[5][ni] = mfma16(al1, bh[ni], acc[5][ni]);
            }
            __builtin_amdgcn_s_setprio(0);
        }
        phase_barrier();

        // ---- phase 3: MFMA mi6,7; counted vmcnt; barrier ----
        {
            const char* rp0 = sA + (wr + 6 * 16 + fr) * 128;
            const char* rp1 = sA + (wr + 7 * 16 + fr) * 128;
            bf16x8 ah0 = *(const bf16x8*)(rp0 + hiSlot), al0 = *(const bf16x8*)(rp0 + loSlot);
            bf16x8 ah1 = *(const bf16x8*)(rp1 + hiSlot), al1 = *(const bf16x8*)(rp1 + loSlot);
            __builtin_amdgcn_s_setprio(1);
            #pragma unroll
            for (int ni = 0; ni < 4; ni++) {
                acc[6][ni] = mfma16(ah0, bh[ni], acc[6][ni]);
                acc[6][ni] = mfma16(ah0, bl[ni], acc[6][ni]);
                acc[6][ni] = mfma16(al0, bh[ni], acc[6][ni]);
                acc[7][ni] = mfma16(ah1, bh[ni], acc[7][ni]);
                acc[7][ni] = mfma16(ah1, bl[ni], acc[7][ni]);
                acc[7][ni] = mfma16(al1, bh[ni], acc[7][ni]);
            }
            __builtin_amdgcn_s_setprio(0);
        }
        __builtin_amdgcn_sched_barrier(0);
        if (t < NT - 2) {
            asm volatile("s_waitcnt vmcnt(6)" ::: "memory");
        } else if (t == NT - 2) {
            asm volatile("s_waitcnt vmcnt(0)" ::: "memory");
        }
        phase_barrier();
    }

    // ---- fused LSTM epilogue ----
    const int lb = lane & ~3;  // quad: lanes lb..lb+3 hold gates f,i,c,o of same h
    const int64_t OFF_H = (int64_t)B_DIM * H_DIM;
    const int64_t OFF_C = (int64_t)2 * B_DIM * H_DIM;
    #pragma unroll
    for (int mi = 0; mi < 8; mi++)
        #pragma unroll
        for (int ni = 0; ni < 4; ni++) {
            int col = n0 + wc + ni * 16 + fr;  // n' = 4h+g
            int g = col & 3;
            int h = col >> 2;
            float bb = bias[col];
            int rowb = m0 + wr + mi * 16 + q * 4;
            #pragma unroll
            for (int j = 0; j < 4; j++) {
                float v = acc[mi][ni][j] + bb;
                float a = (g == 2) ? tanhf(v) : 1.0f / (1.0f + expf(-v));
                float fg = __shfl(a, lb + 0, 64);
                float ig = __shfl(a, lb + 1, 64);
                float ct = __shfl(a, lb + 2, 64);
                float og = __shfl(a, lb + 3, 64);
                int row = rowb + j;
                int64_t o = (int64_t)row * H_DIM + h;
                float cn = fg * cell[o] + ig * ct;
                float hn = og * tanhf(cn);
                int role = lane & 3;
                if (role == 0) {
                    out0[OFF_C + o] = cn;
                } else if (role == 1) {
                    out0[OFF_H + o] = hn;
                } else if (role == 2) {
                    hhi[o] = f2bf(hn);
                } else {
                    unsigned short tt = f2bf(hn);
                    hlo[o] = f2bf(hn - bf2f(tt));
                }
            }
        }
}

// ---------------------------------------------------------------------------
// LOGITS GEMM: bf16x3, 128x128 tile, BK=32, 4 waves (m97 structure).
// A: [M][K] hi/lo.  B: [N][K] hi/lo.  Bias-add epilogue, fp32 store.
// ---------------------------------------------------------------------------
__global__ __launch_bounds__(256, 2) void k_gemm128(
    const unsigned short* __restrict__ Ahi, const unsigned short* __restrict__ Alo,
    const unsigned short* __restrict__ Bhi, const unsigned short* __restrict__ Blo,
    int K, int Ncols,
    const float* __restrict__ bias,
    float* __restrict__ out0) {
    __shared__ char smem[32768];

    const int tid  = threadIdx.x;
    const int lane = tid & 63;
    const int w    = tid >> 6;
    const int wr   = (w >> 1) * 64;
    const int wc   = (w & 1) * 64;
    const int m0   = blockIdx.y * 128;
    const int n0   = blockIdx.x * 128;

    f32x4 acc[4][4];
    #pragma unroll
    for (int i = 0; i < 4; i++)
        #pragma unroll
        for (int j = 0; j < 4; j++) acc[i][j] = (f32x4){0.f, 0.f, 0.f, 0.f};

    const int sr = tid >> 3;
    const int s2 = (tid & 7) ^ (sr & 7);
    const unsigned short* Asrc =
        ((s2 < 4) ? Ahi : Alo) + (int64_t)(m0 + sr) * K + (s2 & 3) * 8;
    const unsigned short* Bsrc =
        ((s2 < 4) ? Bhi : Blo) + (int64_t)(n0 + sr) * K + (s2 & 3) * 8;

    const int q  = lane >> 4;
    const int fr = lane & 15;
    const int sw = lane & 7;
    const int hiSlot = (q ^ sw) << 4;
    const int loSlot = ((q + 4) ^ sw) << 4;

    for (int kt = 0; kt < K; kt += 32) {
        __syncthreads();
        #pragma unroll
        for (int i = 0; i < 4; i++) {
            gload_lds16(Asrc + (int64_t)i * 32 * K + kt, smem + i * 4096 + w * 1024);
            gload_lds16(Bsrc + (int64_t)i * 32 * K + kt, smem + 16384 + i * 4096 + w * 1024);
        }
        __syncthreads();

        bf16x8 ah[4], al[4], bh[4], bl[4];
        #pragma unroll
        for (int mi = 0; mi < 4; mi++) {
            const char* rp = smem + (wr + mi * 16 + fr) * 128;
            ah[mi] = *(const bf16x8*)(rp + hiSlot);
            al[mi] = *(const bf16x8*)(rp + loSlot);
        }
        #pragma unroll
        for (int ni = 0; ni < 4; ni++) {
            const char* rp = smem + 16384 + (wc + ni * 16 + fr) * 128;
            bh[ni] = *(const bf16x8*)(rp + hiSlot);
            bl[ni] = *(const bf16x8*)(rp + loSlot);
        }
        #pragma unroll
        for (int mi = 0; mi < 4; mi++)
            #pragma unroll
            for (int ni = 0; ni < 4; ni++) {
                acc[mi][ni] = mfma16(ah[mi], bh[ni], acc[mi][ni]);
                acc[mi][ni] = mfma16(ah[mi], bl[ni], acc[mi][ni]);
                acc[mi][ni] = mfma16(al[mi], bh[ni], acc[mi][ni]);
            }
    }

    #pragma unroll
    for (int mi = 0; mi < 4; mi++)
        #pragma unroll
        for (int ni = 0; ni < 4; ni++) {
            int col = n0 + wc + ni * 16 + fr;
            int rowb = m0 + wr + mi * 16 + q * 4;
            float bb = bias[col];
            #pragma unroll
            for (int j = 0; j < 4; j++)
                out0[(int64_t)(rowb + j) * Ncols + col] = acc[mi][ni][j] + bb;
        }
}

// ---------------------------------------------------------------------------
// Row-wise log_softmax over [8192][1024]: one block per row.
// ---------------------------------------------------------------------------
__global__ __launch_bounds__(256) void k_logsoftmax(
    const float* __restrict__ logits, float* __restrict__ out) {
    const int row = blockIdx.x;
    const int t = threadIdx.x;
    const float* x = logits + (int64_t)row * 1024;
    float4 v = *(const float4*)(x + t * 4);

    float m = fmaxf(fmaxf(v.x, v.y), fmaxf(v.z, v.w));
    #pragma unroll
    for (int off = 1; off < 64; off <<= 1) m = fmaxf(m, __shfl_xor(m, off, 64));
    __shared__ float sm[4];
    __shared__ float ssum[4];
    int ln = t & 63, wv = t >> 6;
    if (ln == 0) sm[wv] = m;
    __syncthreads();
    m = fmaxf(fmaxf(sm[0], sm[1]), fmaxf(sm[2], sm[3]));

    float s = expf(v.x - m) + expf(v.y - m) + expf(v.z - m) + expf(v.w - m);
    #pragma unroll
    for (int off = 1; off < 64; off <<= 1) s += __shfl_xor(s, off, 64);
    if (ln == 0) ssum[wv] = s;
    __syncthreads();
    s = ssum[0] + ssum[1] + ssum[2] + ssum[3];

    float lse = m + logf(s);
    float4 o;
    o.x = v.x - lse; o.y = v.y - lse; o.z = v.z - lse; o.w = v.w - lse;
    *(float4*)(out + (int64_t)row * 1024 + t * 4) = o;
}

// ---------------------------------------------------------------------------
extern "C" void kernel_launch(void* const* d_in, const int* in_sizes, int n_in,
                              void* d_out, int out_size, void* d_ws, size_t ws_size,
                              hipStream_t stream) {
    const float* input  = (const float*)d_in[0];
    const float* hidden = (const float*)d_in[1];
    const float* cell   = (const float*)d_in[2];
    const float* W_f = (const float*)d_in[3];
    const float* U_f = (const float*)d_in[4];
    const float* b_f = (const float*)d_in[5];
    const float* W_i = (const float*)d_in[6];
    const float* U_i = (const float*)d_in[7];
    const float* b_i = (const float*)d_in[8];
    const float* W_c = (const float*)d_in[9];
    const float* U_c = (const float*)d_in[10];
    const float* b_c = (const float*)d_in[11];
    const float* W_o = (const float*)d_in[12];
    const float* U_o = (const float*)d_in[13];
    const float* b_o = (const float*)d_in[14];
    const float* W_h = (const float*)d_in[15];
    const float* b_h = (const float*)d_in[16];
    float* out = (float*)d_out;

    char* ws = (char*)d_ws;
    unsigned short* xhi  = (unsigned short*)(ws);               // 32 MB
    unsigned short* xlo  = (unsigned short*)(ws + 33554432);    // 32 MB
    unsigned short* wuhi = (unsigned short*)(ws + 67108864);    // 16 MB
    unsigned short* wulo = (unsigned short*)(ws + 83886080);    // 16 MB
    unsigned short* hhi  = (unsigned short*)(ws + 100663296);   // 16 MB
    unsigned short* hlo  = (unsigned short*)(ws + 117440512);   // 16 MB
    unsigned short* whhi = (unsigned short*)(ws + 134217728);   // 2 MB
    unsigned short* whlo = (unsigned short*)(ws + 136314880);   // 2 MB
    float*          bias4 = (float*)(ws + 138412032);           // 16 KB
    float*          logits = (float*)(ws);                      // aliases X
    if (ws_size < (size_t)138428416) return;

    hipFuncSetAttribute((const void*)k_gate_gemm256,
                        hipFuncAttributeMaxDynamicSharedMemorySize, 131072);

    k_split_x<<<2048, 256, 0, stream>>>(input, hidden, xhi, xlo);

    const float* Warr[8] = {W_f, W_i, W_c, W_o, U_f, U_i, U_c, U_o};
    for (int a = 0; a < 8; a++)
        k_trans_split<<<dim3(16, 16), 256, 0, stream>>>(
            Warr[a], wuhi, wulo, 4, a & 3, 2048, (a >> 2) * 1024);
    k_trans_split<<<dim3(16, 16), 256, 0, stream>>>(W_h, whhi, whlo, 1, 0, 1024, 0);
    k_pack_bias<<<16, 256, 0, stream>>>(b_f, b_i, b_c, b_o, bias4);

    // gates GEMM + fused LSTM epilogue: M=8192, N'=4096, K=2048, 512 blocks
    k_gate_gemm256<<<512, 512, 131072, stream>>>(
        xhi, xlo, wuhi, wulo, bias4, cell, out, hhi, hlo);

    // logits GEMM: M=8192, N=1024, K=1024
    k_gemm128<<<dim3(8, 64), 256, 0, stream>>>(
        hhi, hlo, whhi, whlo, 1024, 1024, b_h, logits);

    k_logsoftmax<<<8192, 256, 0, stream>>>(logits, out);
}

// Round 3
// 645.673 us; speedup vs baseline: 1.0531x; 1.0013x over previous
//
#include <hip/hip_runtime.h>
#include <hip/hip_bf16.h>
#include <cstdint>

// ---------------------------------------------------------------------------
// LSTM cell fused forward on MI355X (gfx950).
//   gates = [input|hidden] @ [W;U] + b   (fp32 via 3-product bf16 MFMA emulation)
//   gate GEMM: 256x256 tile, m201-shape phases (reads-before-barrier,
//              2 barriers/phase, counted vmcnt(6), setprio)
//   elementwise LSTM epilogue fused into gate GEMM
//   logits = h_new @ W_h + b_h           (128^2 bf16x3 GEMM)
//   log_softmax row-wise
// ---------------------------------------------------------------------------

#define B_DIM   8192
#define K1      2048   // IN + H
#define N1      4096   // 4*H
#define H_DIM   1024
#define OUT_DIM 1024

typedef __attribute__((ext_vector_type(8))) __bf16 bf16x8;
typedef __attribute__((ext_vector_type(4))) float  f32x4;

__device__ __forceinline__ unsigned short f2bf(float f) {
    unsigned int u = __float_as_uint(f);
    u += 0x7FFFu + ((u >> 16) & 1u);
    return (unsigned short)(u >> 16);
}
__device__ __forceinline__ float bf2f(unsigned short s) {
    return __uint_as_float(((unsigned int)s) << 16);
}

__device__ __forceinline__ void gload_lds16(const void* g, void* l) {
    __builtin_amdgcn_global_load_lds(
        (const __attribute__((address_space(1))) void*)g,
        (__attribute__((address_space(3))) void*)l, 16, 0, 0);
}

__device__ __forceinline__ f32x4 mfma16(bf16x8 a, bf16x8 b, f32x4 c) {
    return __builtin_amdgcn_mfma_f32_16x16x32_bf16(a, b, c, 0, 0, 0);
}

// ---------------------------------------------------------------------------
// Split X = [input | hidden] (row-major [8192][2048]) into bf16 hi/lo.
// ---------------------------------------------------------------------------
__global__ __launch_bounds__(256) void k_split_x(
    const float* __restrict__ input, const float* __restrict__ hidden,
    unsigned short* __restrict__ xhi, unsigned short* __restrict__ xlo) {
    const int64_t n4 = (int64_t)B_DIM * K1 / 4;
    for (int64_t i = (int64_t)blockIdx.x * blockDim.x + threadIdx.x; i < n4;
         i += (int64_t)gridDim.x * blockDim.x) {
        int64_t e = i * 4;
        int row = (int)(e >> 11);
        int col = (int)(e & 2047);
        const float* src = (col < 1024) ? (input + (int64_t)row * 1024 + col)
                                        : (hidden + (int64_t)row * 1024 + (col - 1024));
        float4 v = *(const float4*)src;
        ushort4 hv, lv;
        hv.x = f2bf(v.x); lv.x = f2bf(v.x - bf2f(hv.x));
        hv.y = f2bf(v.y); lv.y = f2bf(v.y - bf2f(hv.y));
        hv.z = f2bf(v.z); lv.z = f2bf(v.z - bf2f(hv.z));
        hv.w = f2bf(v.w); lv.w = f2bf(v.w - bf2f(hv.w));
        *(ushort4*)(xhi + e) = hv;
        *(ushort4*)(xlo + e) = lv;
    }
}

// ---------------------------------------------------------------------------
// Transpose + split a [1024 x 1024] fp32 weight into bf16 hi/lo at
// dst[n'][k], n' = h*nmul + ng, k = koff + klocal.
// ---------------------------------------------------------------------------
__global__ __launch_bounds__(256) void k_trans_split(
    const float* __restrict__ src,
    unsigned short* __restrict__ dhi, unsigned short* __restrict__ dlo,
    int nmul, int ng, int dstK, int koff) {
    __shared__ float t[64][65];
    const int h0 = blockIdx.x * 64;
    const int k0 = blockIdx.y * 64;
    const int tx = threadIdx.x & 63, ty = threadIdx.x >> 6;
    #pragma unroll
    for (int r = ty; r < 64; r += 4)
        t[r][tx] = src[(int64_t)(k0 + r) * 1024 + h0 + tx];
    __syncthreads();
    #pragma unroll
    for (int r = ty; r < 64; r += 4) {
        float v = t[tx][r];
        unsigned short hi = f2bf(v);
        unsigned short lo = f2bf(v - bf2f(hi));
        int64_t o = (int64_t)((h0 + r) * nmul + ng) * dstK + koff + k0 + tx;
        dhi[o] = hi;
        dlo[o] = lo;
    }
}

// bias4[n'] = b_g[h], n' = 4h+g
__global__ __launch_bounds__(256) void k_pack_bias(
    const float* __restrict__ bf_, const float* __restrict__ bi_,
    const float* __restrict__ bc_, const float* __restrict__ bo_,
    float* __restrict__ bias4) {
    int n = blockIdx.x * 256 + threadIdx.x;
    if (n < 4096) {
        int g = n & 3, h = n >> 2;
        const float* p = (g == 0) ? bf_ : (g == 1) ? bi_ : (g == 2) ? bc_ : bo_;
        bias4[n] = p[h];
    }
}

// ---------------------------------------------------------------------------
// GATE GEMM: bf16x3, 256x256 tile, BK=32, 8 waves (2M x 4N).
// m201-shape phases: {ds_read frags; 2 stage loads; barrier; lgkmcnt(0);
// setprio(1) MFMA setprio(0); barrier}; vmcnt(6) once per K-tile.
// LDS row = 128B: [hi 4x16B | lo 4x16B], slot XOR (row&7) swizzle carried on
// the global staging source; linear global_load_lds dest (rule 21).
// ---------------------------------------------------------------------------
#define NT (K1 / 32)  // 64 K-tiles

__global__ __launch_bounds__(512, 2) void k_gate_gemm256(
    const unsigned short* __restrict__ Ahi, const unsigned short* __restrict__ Alo,
    const unsigned short* __restrict__ Bhi, const unsigned short* __restrict__ Blo,
    const float* __restrict__ bias,
    const float* __restrict__ cell,
    float* __restrict__ out0,
    unsigned short* __restrict__ hhi, unsigned short* __restrict__ hlo) {
    extern __shared__ char smem[];  // 131072: buf{0,1} x [A 32KB | B 32KB]

    const int tid  = threadIdx.x;
    const int lane = tid & 63;
    const int w    = tid >> 6;             // wave 0..7
    const int wr   = (w >> 2) * 128;       // wave row offset (2 M-waves)
    const int wc   = (w & 3) * 64;         // wave col offset (4 N-waves)

    // XCD-aware swizzle: 512 blocks, 512%8==0 -> simple form valid
    const int bid = blockIdx.x;
    const int swz = (bid & 7) * 64 + (bid >> 3);
    const int m0  = (swz >> 4) * 256;      // 32 m-panels
    const int n0  = (swz & 15) * 256;      // 16 n-panels

    f32x4 acc[8][4];
    #pragma unroll
    for (int i = 0; i < 8; i++)
        #pragma unroll
        for (int j = 0; j < 4; j++) acc[i][j] = (f32x4){0.f, 0.f, 0.f, 0.f};

    // --- staging source (global side carries the swizzle) ---
    const int sr = tid >> 3;               // 0..63 (row within 64-row chunk)
    const int s2 = (tid & 7) ^ (sr & 7);   // logical slot
    const unsigned short* As =
        ((s2 < 4) ? Ahi : Alo) + (int64_t)(m0 + sr) * K1 + (s2 & 3) * 8;
    const unsigned short* Bs =
        ((s2 < 4) ? Bhi : Blo) + (int64_t)(n0 + sr) * K1 + (s2 & 3) * 8;
    const int ldsOff = tid * 16;           // linear dest within a 8KB chunk

    auto stageA = [&](int buf, int chunk, int kt) {
        gload_lds16(As + (int64_t)chunk * 64 * K1 + kt,
                    smem + buf * 65536 + chunk * 8192 + ldsOff);
    };
    auto stageB = [&](int buf, int chunk, int kt) {
        gload_lds16(Bs + (int64_t)chunk * 64 * K1 + kt,
                    smem + buf * 65536 + 32768 + chunk * 8192 + ldsOff);
    };

    // --- ds_read side swizzle ---
    const int q  = lane >> 4;
    const int fr = lane & 15;
    const int sw = lane & 7;
    const int hiSlot = (q ^ sw) << 4;
    const int loSlot = ((q + 4) ^ sw) << 4;

    // ---- prologue: tile0 fully, tile1 minus A1/A3 ----
    stageB(0, 0, 0); stageB(0, 1, 0); stageB(0, 2, 0); stageB(0, 3, 0);
    stageA(0, 0, 0); stageA(0, 2, 0); stageA(0, 1, 0); stageA(0, 3, 0);
    stageB(1, 0, 32); stageB(1, 1, 32); stageB(1, 2, 32); stageB(1, 3, 32);
    stageA(1, 0, 32); stageA(1, 2, 32);
    asm volatile("s_waitcnt vmcnt(6)" ::: "memory");
    __builtin_amdgcn_sched_barrier(0);
    __builtin_amdgcn_s_barrier();
    __builtin_amdgcn_sched_barrier(0);

// read A fragment pair for row block (mi): ah/al from current sA
#define READ_A(mi, ah, al)                                          \
    {                                                               \
        const char* rp_ = sA + (wr + (mi) * 16 + fr) * 128;         \
        ah = *(const bf16x8*)(rp_ + hiSlot);                        \
        al = *(const bf16x8*)(rp_ + loSlot);                        \
    }

// pre-MFMA barrier + own-read drain, then cluster, then post barrier
#define PRE_BAR()                                                   \
    __builtin_amdgcn_sched_barrier(0);                              \
    __builtin_amdgcn_s_barrier();                                   \
    asm volatile("s_waitcnt lgkmcnt(0)" ::: "memory");              \
    __builtin_amdgcn_sched_barrier(0);

#define POST_BAR()                                                  \
    __builtin_amdgcn_sched_barrier(0);                              \
    __builtin_amdgcn_s_barrier();                                   \
    __builtin_amdgcn_sched_barrier(0);

#define MFMA_PAIR(mA, mB)                                           \
    __builtin_amdgcn_s_setprio(1);                                  \
    _Pragma("unroll")                                               \
    for (int ni = 0; ni < 4; ni++) {                                \
        acc[mA][ni] = mfma16(ah0, bh[ni], acc[mA][ni]);             \
        acc[mA][ni] = mfma16(ah0, bl[ni], acc[mA][ni]);             \
        acc[mA][ni] = mfma16(al0, bh[ni], acc[mA][ni]);             \
        acc[mB][ni] = mfma16(ah1, bh[ni], acc[mB][ni]);             \
        acc[mB][ni] = mfma16(ah1, bl[ni], acc[mB][ni]);             \
        acc[mB][ni] = mfma16(al1, bh[ni], acc[mB][ni]);             \
    }                                                               \
    __builtin_amdgcn_s_setprio(0);

    #pragma unroll 2
    for (int t = 0; t < NT; ++t) {
        const int c = t & 1;
        const char* sA = smem + (c << 16);
        const char* sB = sA + 32768;
        const int ktD = (t + 1) * 32;      // deferred pieces of tile t+1
        const int ktC = (t + 2) * 32;      // prefetch tile t+2

        bf16x8 bh[4], bl[4];
        bf16x8 ah0, al0, ah1, al1;

        // ---- phase 0: read B(all)+A(mi0,1); stage A1/A3(t+1); MFMA mi0,1 ----
        #pragma unroll
        for (int ni = 0; ni < 4; ni++) {
            const char* rp = sB + (wc + ni * 16 + fr) * 128;
            bh[ni] = *(const bf16x8*)(rp + hiSlot);
            bl[ni] = *(const bf16x8*)(rp + loSlot);
        }
        READ_A(0, ah0, al0);
        READ_A(1, ah1, al1);
        if (t < NT - 1) { stageA(c ^ 1, 1, ktD); stageA(c ^ 1, 3, ktD); }
        asm volatile("s_waitcnt lgkmcnt(8)" ::: "memory");  // 12 reads in flight
        PRE_BAR();
        MFMA_PAIR(0, 1);
        POST_BAR();

        // ---- phase 1: read A(mi2,3); stage B0/B1(t+2); MFMA mi2,3 ----
        READ_A(2, ah0, al0);
        READ_A(3, ah1, al1);
        if (t < NT - 2) { stageB(c, 0, ktC); stageB(c, 1, ktC); }
        PRE_BAR();
        MFMA_PAIR(2, 3);
        POST_BAR();

        // ---- phase 2: read A(mi4,5); stage B2/B3(t+2); MFMA mi4,5 ----
        READ_A(4, ah0, al0);
        READ_A(5, ah1, al1);
        if (t < NT - 2) { stageB(c, 2, ktC); stageB(c, 3, ktC); }
        PRE_BAR();
        MFMA_PAIR(4, 5);
        POST_BAR();

        // ---- phase 3: read A(mi6,7); stage A0/A2(t+2); MFMA mi6,7; vmcnt ----
        READ_A(6, ah0, al0);
        READ_A(7, ah1, al1);
        if (t < NT - 2) { stageA(c, 0, ktC); stageA(c, 2, ktC); }
        PRE_BAR();
        MFMA_PAIR(6, 7);
        __builtin_amdgcn_sched_barrier(0);
        if (t < NT - 2) {
            asm volatile("s_waitcnt vmcnt(6)" ::: "memory");
        } else if (t == NT - 2) {
            asm volatile("s_waitcnt vmcnt(0)" ::: "memory");
        }
        POST_BAR();
    }

#undef READ_A
#undef PRE_BAR
#undef POST_BAR
#undef MFMA_PAIR

    // ---- fused LSTM epilogue ----
    const int lb = lane & ~3;  // quad: lanes lb..lb+3 hold gates f,i,c,o of same h
    const int64_t OFF_H = (int64_t)B_DIM * H_DIM;
    const int64_t OFF_C = (int64_t)2 * B_DIM * H_DIM;
    #pragma unroll
    for (int mi = 0; mi < 8; mi++)
        #pragma unroll
        for (int ni = 0; ni < 4; ni++) {
            int col = n0 + wc + ni * 16 + fr;  // n' = 4h+g
            int g = col & 3;
            int h = col >> 2;
            float bb = bias[col];
            int rowb = m0 + wr + mi * 16 + q * 4;
            #pragma unroll
            for (int j = 0; j < 4; j++) {
                float v = acc[mi][ni][j] + bb;
                float a = (g == 2) ? tanhf(v) : 1.0f / (1.0f + expf(-v));
                float fg = __shfl(a, lb + 0, 64);
                float ig = __shfl(a, lb + 1, 64);
                float ct = __shfl(a, lb + 2, 64);
                float og = __shfl(a, lb + 3, 64);
                int row = rowb + j;
                int64_t o = (int64_t)row * H_DIM + h;
                float cn = fg * cell[o] + ig * ct;
                float hn = og * tanhf(cn);
                int role = lane & 3;
                if (role == 0) {
                    out0[OFF_C + o] = cn;
                } else if (role == 1) {
                    out0[OFF_H + o] = hn;
                } else if (role == 2) {
                    hhi[o] = f2bf(hn);
                } else {
                    unsigned short tt = f2bf(hn);
                    hlo[o] = f2bf(hn - bf2f(tt));
                }
            }
        }
}

// ---------------------------------------------------------------------------
// LOGITS GEMM: bf16x3, 128x128 tile, BK=32, 4 waves (m97 structure).
// ---------------------------------------------------------------------------
__global__ __launch_bounds__(256, 2) void k_gemm128(
    const unsigned short* __restrict__ Ahi, const unsigned short* __restrict__ Alo,
    const unsigned short* __restrict__ Bhi, const unsigned short* __restrict__ Blo,
    int K, int Ncols,
    const float* __restrict__ bias,
    float* __restrict__ out0) {
    __shared__ char smem[32768];

    const int tid  = threadIdx.x;
    const int lane = tid & 63;
    const int w    = tid >> 6;
    const int wr   = (w >> 1) * 64;
    const int wc   = (w & 1) * 64;
    const int m0   = blockIdx.y * 128;
    const int n0   = blockIdx.x * 128;

    f32x4 acc[4][4];
    #pragma unroll
    for (int i = 0; i < 4; i++)
        #pragma unroll
        for (int j = 0; j < 4; j++) acc[i][j] = (f32x4){0.f, 0.f, 0.f, 0.f};

    const int sr = tid >> 3;
    const int s2 = (tid & 7) ^ (sr & 7);
    const unsigned short* Asrc =
        ((s2 < 4) ? Ahi : Alo) + (int64_t)(m0 + sr) * K + (s2 & 3) * 8;
    const unsigned short* Bsrc =
        ((s2 < 4) ? Bhi : Blo) + (int64_t)(n0 + sr) * K + (s2 & 3) * 8;

    const int q  = lane >> 4;
    const int fr = lane & 15;
    const int sw = lane & 7;
    const int hiSlot = (q ^ sw) << 4;
    const int loSlot = ((q + 4) ^ sw) << 4;

    for (int kt = 0; kt < K; kt += 32) {
        __syncthreads();
        #pragma unroll
        for (int i = 0; i < 4; i++) {
            gload_lds16(Asrc + (int64_t)i * 32 * K + kt, smem + i * 4096 + w * 1024);
            gload_lds16(Bsrc + (int64_t)i * 32 * K + kt, smem + 16384 + i * 4096 + w * 1024);
        }
        __syncthreads();

        bf16x8 ah[4], al[4], bh[4], bl[4];
        #pragma unroll
        for (int mi = 0; mi < 4; mi++) {
            const char* rp = smem + (wr + mi * 16 + fr) * 128;
            ah[mi] = *(const bf16x8*)(rp + hiSlot);
            al[mi] = *(const bf16x8*)(rp + loSlot);
        }
        #pragma unroll
        for (int ni = 0; ni < 4; ni++) {
            const char* rp = smem + 16384 + (wc + ni * 16 + fr) * 128;
            bh[ni] = *(const bf16x8*)(rp + hiSlot);
            bl[ni] = *(const bf16x8*)(rp + loSlot);
        }
        #pragma unroll
        for (int mi = 0; mi < 4; mi++)
            #pragma unroll
            for (int ni = 0; ni < 4; ni++) {
                acc[mi][ni] = mfma16(ah[mi], bh[ni], acc[mi][ni]);
                acc[mi][ni] = mfma16(ah[mi], bl[ni], acc[mi][ni]);
                acc[mi][ni] = mfma16(al[mi], bh[ni], acc[mi][ni]);
            }
    }

    #pragma unroll
    for (int mi = 0; mi < 4; mi++)
        #pragma unroll
        for (int ni = 0; ni < 4; ni++) {
            int col = n0 + wc + ni * 16 + fr;
            int rowb = m0 + wr + mi * 16 + q * 4;
            float bb = bias[col];
            #pragma unroll
            for (int j = 0; j < 4; j++)
                out0[(int64_t)(rowb + j) * Ncols + col] = acc[mi][ni][j] + bb;
        }
}

// ---------------------------------------------------------------------------
// Row-wise log_softmax over [8192][1024]: one block per row.
// ---------------------------------------------------------------------------
__global__ __launch_bounds__(256) void k_logsoftmax(
    const float* __restrict__ logits, float* __restrict__ out) {
    const int row = blockIdx.x;
    const int t = threadIdx.x;
    const float* x = logits + (int64_t)row * 1024;
    float4 v = *(const float4*)(x + t * 4);

    float m = fmaxf(fmaxf(v.x, v.y), fmaxf(v.z, v.w));
    #pragma unroll
    for (int off = 1; off < 64; off <<= 1) m = fmaxf(m, __shfl_xor(m, off, 64));
    __shared__ float sm[4];
    __shared__ float ssum[4];
    int ln = t & 63, wv = t >> 6;
    if (ln == 0) sm[wv] = m;
    __syncthreads();
    m = fmaxf(fmaxf(sm[0], sm[1]), fmaxf(sm[2], sm[3]));

    float s = expf(v.x - m) + expf(v.y - m) + expf(v.z - m) + expf(v.w - m);
    #pragma unroll
    for (int off = 1; off < 64; off <<= 1) s += __shfl_xor(s, off, 64);
    if (ln == 0) ssum[wv] = s;
    __syncthreads();
    s = ssum[0] + ssum[1] + ssum[2] + ssum[3];

    float lse = m + logf(s);
    float4 o;
    o.x = v.x - lse; o.y = v.y - lse; o.z = v.z - lse; o.w = v.w - lse;
    *(float4*)(out + (int64_t)row * 1024 + t * 4) = o;
}

// ---------------------------------------------------------------------------
extern "C" void kernel_launch(void* const* d_in, const int* in_sizes, int n_in,
                              void* d_out, int out_size, void* d_ws, size_t ws_size,
                              hipStream_t stream) {
    const float* input  = (const float*)d_in[0];
    const float* hidden = (const float*)d_in[1];
    const float* cell   = (const float*)d_in[2];
    const float* W_f = (const float*)d_in[3];
    const float* U_f = (const float*)d_in[4];
    const float* b_f = (const float*)d_in[5];
    const float* W_i = (const float*)d_in[6];
    const float* U_i = (const float*)d_in[7];
    const float* b_i = (const float*)d_in[8];
    const float* W_c = (const float*)d_in[9];
    const float* U_c = (const float*)d_in[10];
    const float* b_c = (const float*)d_in[11];
    const float* W_o = (const float*)d_in[12];
    const float* U_o = (const float*)d_in[13];
    const float* b_o = (const float*)d_in[14];
    const float* W_h = (const float*)d_in[15];
    const float* b_h = (const float*)d_in[16];
    float* out = (float*)d_out;

    char* ws = (char*)d_ws;
    unsigned short* xhi  = (unsigned short*)(ws);               // 32 MB
    unsigned short* xlo  = (unsigned short*)(ws + 33554432);    // 32 MB
    unsigned short* wuhi = (unsigned short*)(ws + 67108864);    // 16 MB
    unsigned short* wulo = (unsigned short*)(ws + 83886080);    // 16 MB
    unsigned short* hhi  = (unsigned short*)(ws + 100663296);   // 16 MB
    unsigned short* hlo  = (unsigned short*)(ws + 117440512);   // 16 MB
    unsigned short* whhi = (unsigned short*)(ws + 134217728);   // 2 MB
    unsigned short* whlo = (unsigned short*)(ws + 136314880);   // 2 MB
    float*          bias4 = (float*)(ws + 138412032);           // 16 KB
    float*          logits = (float*)(ws);                      // aliases X
    if (ws_size < (size_t)138428416) return;

    hipFuncSetAttribute((const void*)k_gate_gemm256,
                        hipFuncAttributeMaxDynamicSharedMemorySize, 131072);

    k_split_x<<<2048, 256, 0, stream>>>(input, hidden, xhi, xlo);

    const float* Warr[8] = {W_f, W_i, W_c, W_o, U_f, U_i, U_c, U_o};
    for (int a = 0; a < 8; a++)
        k_trans_split<<<dim3(16, 16), 256, 0, stream>>>(
            Warr[a], wuhi, wulo, 4, a & 3, 2048, (a >> 2) * 1024);
    k_trans_split<<<dim3(16, 16), 256, 0, stream>>>(W_h, whhi, whlo, 1, 0, 1024, 0);
    k_pack_bias<<<16, 256, 0, stream>>>(b_f, b_i, b_c, b_o, bias4);

    // gates GEMM + fused LSTM epilogue: M=8192, N'=4096, K=2048, 512 blocks
    k_gate_gemm256<<<512, 512, 131072, stream>>>(
        xhi, xlo, wuhi, wulo, bias4, cell, out, hhi, hlo);

    // logits GEMM: M=8192, N=1024, K=1024
    k_gemm128<<<dim3(8, 64), 256, 0, stream>>>(
        hhi, hlo, whhi, whlo, 1024, 1024, b_h, logits);

    k_logsoftmax<<<8192, 256, 0, stream>>>(logits, out);
}